// Round 2
// baseline (232.537 us; speedup 1.0000x reference)
//
#include <hip/hip_runtime.h>

#define HW   9216
#define IMG  96
#define NB   8
#define NK   4

typedef __bf16 bf16x8 __attribute__((ext_vector_type(8)));
typedef float  f32x4  __attribute__((ext_vector_type(4)));

__device__ __forceinline__ unsigned short f2bf(float f) {
    unsigned int u = __float_as_uint(f);
    u += 0x7FFFu + ((u >> 16) & 1u);   // round-to-nearest-even (finite inputs)
    return (unsigned short)(u >> 16);
}

// ---------------------------------------------------------------------------
// Kernel 1: prep (+ folded Wc->bf16 conversion in trailing 64 blocks).
// Per 64-pixel tile:
//   - x [b][c][hw] fp32 -> xbt [b][hw][c] bf16 (pixel-major, DIRECT stores)
//   - 12 dots/pixel (8 flow comps + 4 logits), fp32 exact -> coords + softmax
// Structure: 4 waves; wave g owns channels g*64..g*64+63, staged through LDS
// via global_load_lds (2 phases x 32ch x 64px fp32 = 8KB/wave). One
// s_waitcnt vmcnt(0) per phase, NO barrier (wave reads only its own stage) ->
// waves free-run, each phase puts 8KB/wave in flight (vs 2KB register-bound).
// Thread = one pixel (px=lane): xbt row is 8x16B contiguous register stores;
// the old LDS transpose + 2 barriers + pack pass are gone.
// LDS 32KB (stage; 12KB reduction aliased after barrier) -> 5 blocks/CU.
// ---------------------------------------------------------------------------
extern "C" __global__ __launch_bounds__(256, 5)
void prep_kernel(const float* __restrict__ x,
                 const float* __restrict__ Wc,
                 const float* __restrict__ Woff,
                 const float* __restrict__ boff,
                 const float* __restrict__ Wwt,
                 const float* __restrict__ bwt,
                 unsigned short* __restrict__ xbt,
                 unsigned short* __restrict__ Wcb,
                 float2* __restrict__ coords,
                 float* __restrict__ wts)
{
    __shared__ __align__(16) unsigned char lds_raw[32768];  // 4 waves x 8KB stage

    const int t   = threadIdx.x;
    const int bxr = blockIdx.x;

    if (bxr >= NB * 144) {
        // Wc fp32 -> bf16, row-major [o][c] (A-operand layout). 64 blocks.
        int u = ((bxr - NB * 144) * 256 + t) * 4;
        float4 v = *(const float4*)(Wc + u);
        union { unsigned short h[4]; int2 p; } pk;
        pk.h[0] = f2bf(v.x); pk.h[1] = f2bf(v.y);
        pk.h[2] = f2bf(v.z); pk.h[3] = f2bf(v.w);
        *(int2*)(Wcb + u) = pk.p;
        return;
    }

    const int b    = bxr / 144;
    const int p0   = (bxr % 144) * 64;
    const int lane = t & 63;                                  // = pixel in tile
    const int g    = __builtin_amdgcn_readfirstlane(t >> 6);  // wave strip

    const float* XAf = (const float*)(lds_raw) + g * 2048;    // [32ch][64px] f32

    float acc[12];
    #pragma unroll
    for (int j = 0; j < 12; ++j) acc[j] = 0.f;

    unsigned short* xrow = xbt + ((size_t)b * HW + p0 + lane) * 256 + g * 64;

    #pragma unroll
    for (int phase = 0; phase < 2; ++phase) {
        const int cb = g * 64 + phase * 32;   // first channel of this stage

        // stage 32 rows x 64 px fp32 -> this wave's 8KB LDS region.
        // 8 instructions, 1KB each (4 rows x 256B). LDS dest is linear:
        // byte = (i2*4 + lane>>4)*256 + (lane&15)*16 = i2*1024 + lane*16.
        #pragma unroll
        for (int i2 = 0; i2 < 8; ++i2) {
            const float* src = x + ((size_t)(b * 256 + cb + i2 * 4 + (lane >> 4))) * HW
                                 + p0 + (lane & 15) * 4;
            __builtin_amdgcn_global_load_lds(
                (const __attribute__((address_space(1))) void*)src,
                (__attribute__((address_space(3))) void*)(lds_raw + g * 8192 + i2 * 1024 + lane * 16),
                16, 0, 0);
        }
        asm volatile("s_waitcnt vmcnt(0)" ::: "memory");

        // consume: 32 channels, 12 FMAs each (wave-uniform weight -> s_load),
        // pack bf16 pairs, 4x int4 direct stores to xbt (16B contiguous each).
        #pragma unroll
        for (int s8 = 0; s8 < 4; ++s8) {
            union { unsigned int u[4]; int4 i4; } pk;
            #pragma unroll
            for (int pr = 0; pr < 4; ++pr) {
                const int r = s8 * 8 + pr * 2;
                float v0 = XAf[(r + 0) * 64 + lane];
                float v1 = XAf[(r + 1) * 64 + lane];
                const int c0 = cb + r, c1 = cb + r + 1;
                #pragma unroll
                for (int j = 0; j < 8; ++j)
                    acc[j] += v0 * Woff[j * 256 + c0] + v1 * Woff[j * 256 + c1];
                #pragma unroll
                for (int j = 0; j < 4; ++j)
                    acc[8 + j] += v0 * Wwt[j * 256 + c0] + v1 * Wwt[j * 256 + c1];
                pk.u[pr] = (unsigned int)f2bf(v0) | ((unsigned int)f2bf(v1) << 16);
            }
            *(int4*)(xrow + phase * 32 + s8 * 8) = pk.i4;
        }
    }

    // cross-wave partial-dot reduction; red aliases the stage buffers, so
    // barrier first (all waves must be done reading their stage regions).
    __syncthreads();
    float* red = (float*)lds_raw;                 // [4][64][12] = 12288 B
    #pragma unroll
    for (int j = 0; j < 12; ++j)
        red[(g * 64 + lane) * 12 + j] = acc[j];
    __syncthreads();

    if (t < 64) {
        float s[12];
        #pragma unroll
        for (int j = 0; j < 12; ++j)
            s[j] = red[(0 * 64 + lane) * 12 + j] + red[(1 * 64 + lane) * 12 + j] +
                   red[(2 * 64 + lane) * 12 + j] + red[(3 * 64 + lane) * 12 + j];

        const int p = p0 + lane;
        const float pyf = (float)(p / IMG);
        const float pxf = (float)(p % IMG);

        #pragma unroll
        for (int k = 0; k < NK; ++k) {
            float fx = s[k * 2 + 0] + boff[k * 2 + 0];
            float fy = s[k * 2 + 1] + boff[k * 2 + 1];
            float vx = 2.0f * (pxf + fx) / 95.0f - 1.0f;
            float vy = 2.0f * (pyf + fy) / 95.0f - 1.0f;
            float ix = (vx + 1.0f) * 48.0f - 0.5f;
            float iy = (vy + 1.0f) * 48.0f - 0.5f;
            coords[((size_t)k * NB + b) * HW + p] = make_float2(ix, iy);
        }
        float l0 = s[8] + bwt[0], l1 = s[9] + bwt[1];
        float l2 = s[10] + bwt[2], l3 = s[11] + bwt[3];
        float m = fmaxf(fmaxf(l0, l1), fmaxf(l2, l3));
        float e0 = __expf(l0 - m), e1 = __expf(l1 - m);
        float e2 = __expf(l2 - m), e3 = __expf(l3 - m);
        float inv = 1.0f / (e0 + e1 + e2 + e3);
        wts[((size_t)0 * NB + b) * HW + p] = e0 * inv;
        wts[((size_t)1 * NB + b) * HW + p] = e1 * inv;
        wts[((size_t)2 * NB + b) * HW + p] = e2 * inv;
        wts[((size_t)3 * NB + b) * HW + p] = e3 * inv;
    }
}

// ---------------------------------------------------------------------------
// Kernel 2: bilinear sample on x (pixel-major bf16), softmax-weighted:
//   xs[b][p][c] = sum_{16 corners} w_j(p) * xbt[b][idx_j(p)][c]
//   Also writes wsum[b][p] = sum_j w_j into the dead wts[k=0] slice.
// block 256 = 8 px x 32 c-chunks(8c). grid NB*1152.
// ---------------------------------------------------------------------------
extern "C" __global__ __launch_bounds__(256)
void sample_kernel(const unsigned short* __restrict__ xbt,
                   const float2* __restrict__ coords,
                   float* __restrict__ wts,
                   unsigned short* __restrict__ xs)
{
    const int t  = threadIdx.x;
    const int b  = blockIdx.x / 1152;
    const int p0 = (blockIdx.x % 1152) * 8;
    const int pxl = t >> 5, ch = t & 31;
    const int p  = p0 + pxl;

    int   idx[16];
    float w[16];
    #pragma unroll
    for (int k = 0; k < NK; ++k) {
        float2 cc = coords[((size_t)k * NB + b) * HW + p];
        float wk  = wts[((size_t)k * NB + b) * HW + p];
        float x0f = floorf(cc.x), y0f = floorf(cc.y);
        float wx1 = cc.x - x0f, wx0 = 1.0f - wx1;
        float wy1 = cc.y - y0f, wy0 = 1.0f - wy1;
        int x0 = (int)x0f, y0 = (int)y0f;
        int x1 = x0 + 1,   y1 = y0 + 1;
        float vx0 = (x0 >= 0 && x0 < IMG) ? 1.f : 0.f;
        float vx1 = (x1 >= 0 && x1 < IMG) ? 1.f : 0.f;
        float vy0 = (y0 >= 0 && y0 < IMG) ? 1.f : 0.f;
        float vy1 = (y1 >= 0 && y1 < IMG) ? 1.f : 0.f;
        int cx0 = min(max(x0, 0), IMG - 1), cx1 = min(max(x1, 0), IMG - 1);
        int cy0 = min(max(y0, 0), IMG - 1), cy1 = min(max(y1, 0), IMG - 1);
        idx[k * 4 + 0] = cy0 * IMG + cx0;  w[k * 4 + 0] = wk * wx0 * wy0 * vx0 * vy0;
        idx[k * 4 + 1] = cy0 * IMG + cx1;  w[k * 4 + 1] = wk * wx1 * wy0 * vx1 * vy0;
        idx[k * 4 + 2] = cy1 * IMG + cx0;  w[k * 4 + 2] = wk * wx0 * wy1 * vx0 * vy1;
        idx[k * 4 + 3] = cy1 * IMG + cx1;  w[k * 4 + 3] = wk * wx1 * wy1 * vx1 * vy1;
    }

    const unsigned short* base = xbt + (size_t)b * HW * 256 + ch * 8;
    float acc[8];
    #pragma unroll
    for (int i = 0; i < 8; ++i) acc[i] = 0.f;

    #pragma unroll
    for (int j = 0; j < 16; ++j) {
        int4 v = *(const int4*)(base + (size_t)idx[j] * 256);
        const unsigned int* u = (const unsigned int*)&v;
        float wj = w[j];
        #pragma unroll
        for (int q = 0; q < 4; ++q) {
            float lo = __uint_as_float(u[q] << 16);
            float hi = __uint_as_float(u[q] & 0xFFFF0000u);
            acc[2 * q + 0] += wj * lo;
            acc[2 * q + 1] += wj * hi;
        }
    }

    union { unsigned short h[8]; int4 v; } pk;
    #pragma unroll
    for (int i = 0; i < 8; ++i) pk.h[i] = f2bf(acc[i]);
    *(int4*)(xs + ((size_t)b * HW + p) * 256 + ch * 8) = pk.v;

    if (ch == 0) {
        float wsum = 0.f;
        #pragma unroll
        for (int j = 0; j < 16; ++j) wsum += w[j];
        // dead k=0 slice; all reads of it happened earlier in this same wave
        wts[(size_t)b * HW + p] = wsum;
    }
}

// ---------------------------------------------------------------------------
// Kernel 3: bf16 MFMA GEMM: out[b][o][p] = sum_c Wc[o][c]*xs[b][p][c]
//                                        + bc[o]*wsum[b][p]   (fp32 out)
// 128x128 tile, BK=32, 4 waves x (4x4 of 16x16x32).
// Staging via global_load_lds width=16 (LDS dest = wave base + lane*16B).
// ---------------------------------------------------------------------------
extern "C" __global__ __launch_bounds__(256)
void gemm_kernel(const unsigned short* __restrict__ Wcb,
                 const unsigned short* __restrict__ xs,
                 const float* __restrict__ bc,
                 const float* __restrict__ wts,   // k=0 slice = wsum[b][p]
                 float* __restrict__ out)
{
    __shared__ __align__(16) unsigned short As[128 * 32];
    __shared__ __align__(16) unsigned short Bs[128 * 32];

    const int t  = threadIdx.x;
    const int bx = blockIdx.x;
    const int b  = bx / 144;
    const int r  = bx % 144;
    const int m0 = (r / 72) * 128;   // o tile
    const int p0 = (r % 72) * 128;   // p tile

    const int lane = t & 63, wave = t >> 6;
    const int wm = (wave >> 1) * 64, wn = (wave & 1) * 64;
    const int l15 = lane & 15, quad = lane >> 4;

    f32x4 acc[4][4];
    #pragma unroll
    for (int mt = 0; mt < 4; ++mt)
        #pragma unroll
        for (int nt = 0; nt < 4; ++nt)
            acc[mt][nt] = (f32x4){0.f, 0.f, 0.f, 0.f};

    const unsigned short* aBase = Wcb + (size_t)m0 * 256;
    const unsigned short* bBase = xs + ((size_t)b * HW + p0) * 256;

    for (int k0 = 0; k0 < 256; k0 += 32) {
        #pragma unroll
        for (int i = 0; i < 2; ++i) {
            int u = t + 256 * i;          // 512 tasks x 16B; LDS = wave base + lane*16
            int row = u >> 2, sub = u & 3;
            __builtin_amdgcn_global_load_lds(
                (const __attribute__((address_space(1))) void*)(aBase + (size_t)row * 256 + k0 + sub * 8),
                (__attribute__((address_space(3))) void*)(As + u * 8), 16, 0, 0);
            __builtin_amdgcn_global_load_lds(
                (const __attribute__((address_space(1))) void*)(bBase + (size_t)row * 256 + k0 + sub * 8),
                (__attribute__((address_space(3))) void*)(Bs + u * 8), 16, 0, 0);
        }
        __syncthreads();
        bf16x8 af[4], bf[4];
        #pragma unroll
        for (int mt = 0; mt < 4; ++mt)
            af[mt] = *(const bf16x8*)(const void*)(As + (wm + mt * 16 + l15) * 32 + quad * 8);
        #pragma unroll
        for (int nt = 0; nt < 4; ++nt)
            bf[nt] = *(const bf16x8*)(const void*)(Bs + (wn + nt * 16 + l15) * 32 + quad * 8);
        #pragma unroll
        for (int mt = 0; mt < 4; ++mt)
            #pragma unroll
            for (int nt = 0; nt < 4; ++nt)
                acc[mt][nt] = __builtin_amdgcn_mfma_f32_16x16x32_bf16(af[mt], bf[nt], acc[mt][nt], 0, 0, 0);
        __syncthreads();
    }

    // wsum for this thread's 4 p-columns
    float wv[4];
    #pragma unroll
    for (int nt = 0; nt < 4; ++nt)
        wv[nt] = wts[(size_t)b * HW + p0 + wn + nt * 16 + l15];

    // epilogue: D row = quad*4+reg (o), col = l15 (p); fp32 out + bias*wsum
    #pragma unroll
    for (int mt = 0; mt < 4; ++mt) {
        int ob = m0 + wm + mt * 16 + quad * 4;
        #pragma unroll
        for (int reg = 0; reg < 4; ++reg) {
            int o = ob + reg;
            float bias = bc[o];
            float* dst = out + ((size_t)b * 256 + o) * HW + p0 + wn + l15;
            #pragma unroll
            for (int nt = 0; nt < 4; ++nt)
                dst[nt * 16] = acc[mt][nt][reg] + bias * wv[nt];
        }
    }
}

// ---------------------------------------------------------------------------
extern "C" void kernel_launch(void* const* d_in, const int* in_sizes, int n_in,
                              void* d_out, int out_size, void* d_ws, size_t ws_size,
                              hipStream_t stream)
{
    const float* x    = (const float*)d_in[0];
    const float* Wc   = (const float*)d_in[1];
    const float* bc   = (const float*)d_in[2];
    const float* Woff = (const float*)d_in[3];
    const float* boff = (const float*)d_in[4];
    const float* Wwt  = (const float*)d_in[5];
    const float* bwt  = (const float*)d_in[6];
    float* out = (float*)d_out;

    char* ws = (char*)d_ws;
    unsigned short* xbt  = (unsigned short*)(ws);               // 37748736 B
    unsigned short* xs   = (unsigned short*)(ws + 37748736);    // 37748736 B
    float2* coords       = (float2*)(ws + 75497472);            // 2359296 B
    float*  wts          = (float*)(ws + 77856768);             // 1179648 B
    unsigned short* Wcb  = (unsigned short*)(ws + 79036416);    // 131072 B

    prep_kernel<<<dim3(NB * 144 + 64), dim3(256), 0, stream>>>(
        x, Wc, Woff, boff, Wwt, bwt, xbt, Wcb, coords, wts);
    sample_kernel<<<dim3(NB * 1152), dim3(256), 0, stream>>>(xbt, coords, wts, xs);
    gemm_kernel<<<dim3(NB * 144), dim3(256), 0, stream>>>(Wcb, xs, bc, wts, out);
}

// Round 3
// 211.487 us; speedup vs baseline: 1.0995x; 1.0995x over previous
//
#include <hip/hip_runtime.h>

#define HW   9216
#define IMG  96
#define NB   8
#define NK   4

typedef __bf16 bf16x8 __attribute__((ext_vector_type(8)));
typedef float  f32x4  __attribute__((ext_vector_type(4)));

__device__ __forceinline__ unsigned short f2bf(float f) {
    unsigned int u = __float_as_uint(f);
    u += 0x7FFFu + ((u >> 16) & 1u);   // round-to-nearest-even (finite inputs)
    return (unsigned short)(u >> 16);
}

// ---------------------------------------------------------------------------
// Kernel 1: prep (+ folded Wc->bf16 conversion in trailing 64 blocks).
// REVERTED to the round-0 structure (best measured 56.7 us): LDS transpose
// tile with coalesced xbt writes; 8 loads in flight per iter.
// ---------------------------------------------------------------------------
extern "C" __global__ __launch_bounds__(256, 4)
void prep_kernel(const float* __restrict__ x,
                 const float* __restrict__ Wc,
                 const float* __restrict__ Woff,
                 const float* __restrict__ boff,
                 const float* __restrict__ Wwt,
                 const float* __restrict__ bwt,
                 unsigned short* __restrict__ xbt,
                 unsigned short* __restrict__ Wcb,
                 float2* __restrict__ coords,
                 float* __restrict__ wts)
{
    __shared__ __align__(16) unsigned short tile[64 * 264];   // 33792 B

    const int t   = threadIdx.x;
    const int bxr = blockIdx.x;

    if (bxr >= NB * 144) {
        // Wc fp32 -> bf16, row-major [o][c] (A-operand layout). 64 blocks.
        int u = ((bxr - NB * 144) * 256 + t) * 4;
        float4 v = *(const float4*)(Wc + u);
        union { unsigned short h[4]; int2 p; } pk;
        pk.h[0] = f2bf(v.x); pk.h[1] = f2bf(v.y);
        pk.h[2] = f2bf(v.z); pk.h[3] = f2bf(v.w);
        *(int2*)(Wcb + u) = pk.p;
        return;
    }

    const int b  = bxr / 144;
    const int p0 = (bxr % 144) * 64;
    const int px = t & 63;
    const int g  = __builtin_amdgcn_readfirstlane(t >> 6);  // wave-uniform strip

    float acc[12];
    #pragma unroll
    for (int j = 0; j < 12; ++j) acc[j] = 0.f;

    const float* xb = x + ((size_t)(b * 256 + g * 64)) * HW + p0 + px;
    unsigned int* trow = (unsigned int*)tile;

    for (int i0 = 0; i0 < 64; i0 += 8) {
        float v[8];
        #pragma unroll
        for (int q = 0; q < 8; ++q)
            v[q] = xb[(size_t)(i0 + q) * HW];     // 8 independent loads in flight
        #pragma unroll
        for (int q = 0; q < 8; ++q) {
            const int c = g * 64 + i0 + q;        // wave-uniform -> scalar wt loads
            #pragma unroll
            for (int j = 0; j < 8; ++j) acc[j] += v[q] * Woff[j * 256 + c];
            #pragma unroll
            for (int j = 0; j < 4; ++j) acc[8 + j] += v[q] * Wwt[j * 256 + c];
        }
        #pragma unroll
        for (int q = 0; q < 8; q += 2) {
            unsigned int pk = (unsigned int)f2bf(v[q]) | ((unsigned int)f2bf(v[q + 1]) << 16);
            trow[px * 132 + ((g * 64 + i0 + q) >> 1)] = pk;
        }
    }

    __syncthreads();
    // pack xbt: 64 px x 256 c bf16, int4 stores (lanes 0-31 = contiguous 512 B)
    #pragma unroll
    for (int r = 0; r < 8; ++r) {
        int u = t + 256 * r;
        int sub = u & 31, p2 = u >> 5;
        int4 v = *(const int4*)(tile + p2 * 264 + sub * 8);
        *(int4*)(xbt + ((size_t)b * HW + p0 + p2) * 256 + sub * 8) = v;
    }
    __syncthreads();

    // cross-wave partial-dot reduction through re-used tile memory (12288 B)
    float* red = (float*)tile;
    #pragma unroll
    for (int j = 0; j < 12; ++j)
        red[(g * 64 + px) * 12 + j] = acc[j];
    __syncthreads();

    if (t < 64) {
        float s[12];
        #pragma unroll
        for (int j = 0; j < 12; ++j)
            s[j] = red[(0 * 64 + px) * 12 + j] + red[(1 * 64 + px) * 12 + j] +
                   red[(2 * 64 + px) * 12 + j] + red[(3 * 64 + px) * 12 + j];

        const int p = p0 + px;
        const float pyf = (float)(p / IMG);
        const float pxf = (float)(p % IMG);

        #pragma unroll
        for (int k = 0; k < NK; ++k) {
            float fx = s[k * 2 + 0] + boff[k * 2 + 0];
            float fy = s[k * 2 + 1] + boff[k * 2 + 1];
            float vx = 2.0f * (pxf + fx) / 95.0f - 1.0f;
            float vy = 2.0f * (pyf + fy) / 95.0f - 1.0f;
            float ix = (vx + 1.0f) * 48.0f - 0.5f;
            float iy = (vy + 1.0f) * 48.0f - 0.5f;
            coords[((size_t)k * NB + b) * HW + p] = make_float2(ix, iy);
        }
        float l0 = s[8] + bwt[0], l1 = s[9] + bwt[1];
        float l2 = s[10] + bwt[2], l3 = s[11] + bwt[3];
        float m = fmaxf(fmaxf(l0, l1), fmaxf(l2, l3));
        float e0 = __expf(l0 - m), e1 = __expf(l1 - m);
        float e2 = __expf(l2 - m), e3 = __expf(l3 - m);
        float inv = 1.0f / (e0 + e1 + e2 + e3);
        wts[((size_t)0 * NB + b) * HW + p] = e0 * inv;
        wts[((size_t)1 * NB + b) * HW + p] = e1 * inv;
        wts[((size_t)2 * NB + b) * HW + p] = e2 * inv;
        wts[((size_t)3 * NB + b) * HW + p] = e3 * inv;
    }
}

// ---------------------------------------------------------------------------
// Kernel 2 (FUSED sample+gemm):
//   Per block (128 o x 128 p tile):
//     phase A: coords/weights for 128 px computed once -> LDS (cw/ci/wsum)
//     phase B: bilinear gather from xbt -> Bs_full[128 px][256 c] bf16 in LDS
//              (16B-chunk XOR swizzle: pos = chunk ^ (px&7), kills the
//               512B-row-stride bank conflict on B-fragment ds_read_b128)
//     phase C: K-loop, As staged per 32-k step via global_load_lds with
//              SOURCE-preswizzle (chunk sub^((row>>1)&3)); 16 MFMA / step.
//   Epilogue: out = acc + bc[o]*wsum[p] (wsum from LDS).
// LDS: Bs 65536 + (As 8192 aliased under coords 12288) + wsum 512 = 78336 B
//      -> 2 blocks/CU; sampling of one block overlaps MFMA of the other.
// ---------------------------------------------------------------------------
extern "C" __global__ __launch_bounds__(256, 2)
void fused_kernel(const unsigned short* __restrict__ Wcb,
                  const unsigned short* __restrict__ xbt,
                  const float2* __restrict__ coords,
                  const float* __restrict__ wts,
                  const float* __restrict__ bc,
                  float* __restrict__ out)
{
    __shared__ __align__(16) unsigned char lds[78336];
    unsigned short* BsU  = (unsigned short*)lds;              // [128][256] bf16 swz
    unsigned short* AsU  = (unsigned short*)(lds + 65536);    // [128][32] bf16 (K-loop)
    float*          cw   = (float*)(lds + 65536);             // [128][16] w   (sampling)
    unsigned int*   ci   = (unsigned int*)(lds + 65536 + 8192); // [128][8] idx-pairs
    float*          wsumL= (float*)(lds + 77824);             // [128]

    const int t  = threadIdx.x;
    const int bx = blockIdx.x;
    const int b  = bx / 144;
    const int r  = bx % 144;
    const int m0 = (r / 72) * 128;   // o tile
    const int p0 = (r % 72) * 128;   // p tile

    // ---------------- phase A: per-pixel coords/weights (once per px) ------
    if (t < 128) {
        const int px = t;
        const int p  = p0 + px;
        float wsum_acc = 0.f;
        #pragma unroll
        for (int k = 0; k < NK; ++k) {
            float2 cc = coords[((size_t)k * NB + b) * HW + p];
            float wk  = wts[((size_t)k * NB + b) * HW + p];
            float x0f = floorf(cc.x), y0f = floorf(cc.y);
            float wx1 = cc.x - x0f, wx0 = 1.0f - wx1;
            float wy1 = cc.y - y0f, wy0 = 1.0f - wy1;
            int x0 = (int)x0f, y0 = (int)y0f;
            int x1 = x0 + 1,   y1 = y0 + 1;
            float vx0 = (x0 >= 0 && x0 < IMG) ? 1.f : 0.f;
            float vx1 = (x1 >= 0 && x1 < IMG) ? 1.f : 0.f;
            float vy0 = (y0 >= 0 && y0 < IMG) ? 1.f : 0.f;
            float vy1 = (y1 >= 0 && y1 < IMG) ? 1.f : 0.f;
            int cx0 = min(max(x0, 0), IMG - 1), cx1 = min(max(x1, 0), IMG - 1);
            int cy0 = min(max(y0, 0), IMG - 1), cy1 = min(max(y1, 0), IMG - 1);
            int i0 = cy0 * IMG + cx0, i1 = cy0 * IMG + cx1;
            int i2 = cy1 * IMG + cx0, i3 = cy1 * IMG + cx1;
            float w0 = wk * wx0 * wy0 * vx0 * vy0;
            float w1 = wk * wx1 * wy0 * vx1 * vy0;
            float w2 = wk * wx0 * wy1 * vx0 * vy1;
            float w3 = wk * wx1 * wy1 * vx1 * vy1;
            float4 wv4 = make_float4(w0, w1, w2, w3);
            *(float4*)(cw + px * 16 + k * 4) = wv4;
            uint2 ip;
            ip.x = (unsigned int)i0 | ((unsigned int)i1 << 16);
            ip.y = (unsigned int)i2 | ((unsigned int)i3 << 16);
            *(uint2*)(ci + px * 8 + k * 2) = ip;
            wsum_acc += w0 + w1 + w2 + w3;
        }
        wsumL[px] = wsum_acc;
    }
    __syncthreads();

    // ---------------- phase B: gather -> Bs_full (swizzled) ----------------
    {
        const int pxl = t >> 5, ch = t & 31;
        const unsigned short* gbase = xbt + (size_t)b * HW * 256 + ch * 8;
        #pragma unroll 2
        for (int rep = 0; rep < 16; ++rep) {
            const int px = rep * 8 + pxl;
            float wl[16];
            #pragma unroll
            for (int q = 0; q < 4; ++q) {
                float4 wv = *(const float4*)(cw + px * 16 + q * 4);
                wl[q * 4 + 0] = wv.x; wl[q * 4 + 1] = wv.y;
                wl[q * 4 + 2] = wv.z; wl[q * 4 + 3] = wv.w;
            }
            unsigned int ip[8];
            #pragma unroll
            for (int q = 0; q < 2; ++q) {
                uint4 iv = *(const uint4*)(ci + px * 8 + q * 4);
                ip[q * 4 + 0] = iv.x; ip[q * 4 + 1] = iv.y;
                ip[q * 4 + 2] = iv.z; ip[q * 4 + 3] = iv.w;
            }
            int4 v[16];
            #pragma unroll
            for (int j = 0; j < 16; ++j) {
                unsigned int idx = (ip[j >> 1] >> ((j & 1) * 16)) & 0xFFFFu;
                v[j] = *(const int4*)(gbase + (size_t)idx * 256);
            }
            float acc[8];
            #pragma unroll
            for (int i = 0; i < 8; ++i) acc[i] = 0.f;
            #pragma unroll
            for (int j = 0; j < 16; ++j) {
                const unsigned int* u = (const unsigned int*)&v[j];
                float wj = wl[j];
                #pragma unroll
                for (int q = 0; q < 4; ++q) {
                    float lo = __uint_as_float(u[q] << 16);
                    float hi = __uint_as_float(u[q] & 0xFFFF0000u);
                    acc[2 * q + 0] += wj * lo;
                    acc[2 * q + 1] += wj * hi;
                }
            }
            union { unsigned short h[8]; int4 v4; } pk;
            #pragma unroll
            for (int i = 0; i < 8; ++i) pk.h[i] = f2bf(acc[i]);
            const int pos = ch ^ (px & 7);
            *(int4*)(BsU + px * 256 + pos * 8) = pk.v4;
        }
    }
    __syncthreads();

    // ---------------- phase C: MFMA K-loop ---------------------------------
    const int lane = t & 63, wave = t >> 6;
    const int wm = (wave >> 1) * 64, wn = (wave & 1) * 64;
    const int l15 = lane & 15, quad = lane >> 4;

    f32x4 acc[4][4];
    #pragma unroll
    for (int mt = 0; mt < 4; ++mt)
        #pragma unroll
        for (int nt = 0; nt < 4; ++nt)
            acc[mt][nt] = (f32x4){0.f, 0.f, 0.f, 0.f};

    const unsigned short* aBase = Wcb + (size_t)m0 * 256;

    for (int k0 = 0; k0 < 256; k0 += 32) {
        #pragma unroll
        for (int i = 0; i < 2; ++i) {
            int u = t + 256 * i;              // 512 tasks x 16B, linear LDS dest
            int row = u >> 2, sub = u & 3;
            int sub_g = sub ^ ((row >> 1) & 3);   // source-preswizzle
            __builtin_amdgcn_global_load_lds(
                (const __attribute__((address_space(1))) void*)(aBase + (size_t)row * 256 + k0 + sub_g * 8),
                (__attribute__((address_space(3))) void*)(AsU + u * 8), 16, 0, 0);
        }
        __syncthreads();
        bf16x8 af[4], bf[4];
        #pragma unroll
        for (int mt = 0; mt < 4; ++mt) {
            int row = wm + mt * 16 + l15;
            int cch = quad ^ ((row >> 1) & 3);
            af[mt] = *(const bf16x8*)(const void*)(AsU + row * 32 + cch * 8);
        }
        #pragma unroll
        for (int nt = 0; nt < 4; ++nt) {
            int row = wn + nt * 16 + l15;
            int pos = ((k0 >> 3) + quad) ^ (row & 7);
            bf[nt] = *(const bf16x8*)(const void*)(BsU + row * 256 + pos * 8);
        }
        #pragma unroll
        for (int mt = 0; mt < 4; ++mt)
            #pragma unroll
            for (int nt = 0; nt < 4; ++nt)
                acc[mt][nt] = __builtin_amdgcn_mfma_f32_16x16x32_bf16(af[mt], bf[nt], acc[mt][nt], 0, 0, 0);
        __syncthreads();
    }

    // wsum for this thread's 4 p-columns (from LDS)
    float wv[4];
    #pragma unroll
    for (int nt = 0; nt < 4; ++nt)
        wv[nt] = wsumL[wn + nt * 16 + l15];

    // epilogue: D row = quad*4+reg (o), col = l15 (p); fp32 out + bias*wsum
    #pragma unroll
    for (int mt = 0; mt < 4; ++mt) {
        int ob = m0 + wm + mt * 16 + quad * 4;
        #pragma unroll
        for (int reg = 0; reg < 4; ++reg) {
            int o = ob + reg;
            float bias = bc[o];
            float* dst = out + ((size_t)b * 256 + o) * HW + p0 + wn + l15;
            #pragma unroll
            for (int nt = 0; nt < 4; ++nt)
                dst[nt * 16] = acc[mt][nt][reg] + bias * wv[nt];
        }
    }
}

// ---------------------------------------------------------------------------
extern "C" void kernel_launch(void* const* d_in, const int* in_sizes, int n_in,
                              void* d_out, int out_size, void* d_ws, size_t ws_size,
                              hipStream_t stream)
{
    const float* x    = (const float*)d_in[0];
    const float* Wc   = (const float*)d_in[1];
    const float* bc   = (const float*)d_in[2];
    const float* Woff = (const float*)d_in[3];
    const float* boff = (const float*)d_in[4];
    const float* Wwt  = (const float*)d_in[5];
    const float* bwt  = (const float*)d_in[6];
    float* out = (float*)d_out;

    char* ws = (char*)d_ws;
    unsigned short* xbt  = (unsigned short*)(ws);               // 37748736 B
    float2* coords       = (float2*)(ws + 75497472);            // 2359296 B
    float*  wts          = (float*)(ws + 77856768);             // 1179648 B
    unsigned short* Wcb  = (unsigned short*)(ws + 79036416);    // 131072 B

    prep_kernel<<<dim3(NB * 144 + 64), dim3(256), 0, stream>>>(
        x, Wc, Woff, boff, Wwt, bwt, xbt, Wcb, coords, wts);
    fused_kernel<<<dim3(NB * 144), dim3(256), 0, stream>>>(
        Wcb, xbt, coords, wts, bc, out);
}

// Round 4
// 196.585 us; speedup vs baseline: 1.1829x; 1.0758x over previous
//
#include <hip/hip_runtime.h>

#define HW   9216
#define IMG  96
#define NB   8
#define NK   4

typedef __bf16 bf16x8 __attribute__((ext_vector_type(8)));
typedef float  f32x4  __attribute__((ext_vector_type(4)));

__device__ __forceinline__ unsigned short f2bf(float f) {
    unsigned int u = __float_as_uint(f);
    u += 0x7FFFu + ((u >> 16) & 1u);   // round-to-nearest-even (finite inputs)
    return (unsigned short)(u >> 16);
}

// ---------------------------------------------------------------------------
// Kernel 1: prep (+ folded Wc->bf16 conversion in trailing 64 blocks).
// Round-0 structure (best measured 56.7 us): LDS transpose tile with
// coalesced xbt writes; 8 loads in flight per iter. DO NOT TOUCH.
// ---------------------------------------------------------------------------
extern "C" __global__ __launch_bounds__(256, 4)
void prep_kernel(const float* __restrict__ x,
                 const float* __restrict__ Wc,
                 const float* __restrict__ Woff,
                 const float* __restrict__ boff,
                 const float* __restrict__ Wwt,
                 const float* __restrict__ bwt,
                 unsigned short* __restrict__ xbt,
                 unsigned short* __restrict__ Wcb,
                 float2* __restrict__ coords,
                 float* __restrict__ wts)
{
    __shared__ __align__(16) unsigned short tile[64 * 264];   // 33792 B

    const int t   = threadIdx.x;
    const int bxr = blockIdx.x;

    if (bxr >= NB * 144) {
        // Wc fp32 -> bf16, row-major [o][c] (A-operand layout). 64 blocks.
        int u = ((bxr - NB * 144) * 256 + t) * 4;
        float4 v = *(const float4*)(Wc + u);
        union { unsigned short h[4]; int2 p; } pk;
        pk.h[0] = f2bf(v.x); pk.h[1] = f2bf(v.y);
        pk.h[2] = f2bf(v.z); pk.h[3] = f2bf(v.w);
        *(int2*)(Wcb + u) = pk.p;
        return;
    }

    const int b  = bxr / 144;
    const int p0 = (bxr % 144) * 64;
    const int px = t & 63;
    const int g  = __builtin_amdgcn_readfirstlane(t >> 6);  // wave-uniform strip

    float acc[12];
    #pragma unroll
    for (int j = 0; j < 12; ++j) acc[j] = 0.f;

    const float* xb = x + ((size_t)(b * 256 + g * 64)) * HW + p0 + px;
    unsigned int* trow = (unsigned int*)tile;

    for (int i0 = 0; i0 < 64; i0 += 8) {
        float v[8];
        #pragma unroll
        for (int q = 0; q < 8; ++q)
            v[q] = xb[(size_t)(i0 + q) * HW];     // 8 independent loads in flight
        #pragma unroll
        for (int q = 0; q < 8; ++q) {
            const int c = g * 64 + i0 + q;        // wave-uniform -> scalar wt loads
            #pragma unroll
            for (int j = 0; j < 8; ++j) acc[j] += v[q] * Woff[j * 256 + c];
            #pragma unroll
            for (int j = 0; j < 4; ++j) acc[8 + j] += v[q] * Wwt[j * 256 + c];
        }
        #pragma unroll
        for (int q = 0; q < 8; q += 2) {
            unsigned int pk = (unsigned int)f2bf(v[q]) | ((unsigned int)f2bf(v[q + 1]) << 16);
            trow[px * 132 + ((g * 64 + i0 + q) >> 1)] = pk;
        }
    }

    __syncthreads();
    // pack xbt: 64 px x 256 c bf16, int4 stores (lanes 0-31 = contiguous 512 B)
    #pragma unroll
    for (int r = 0; r < 8; ++r) {
        int u = t + 256 * r;
        int sub = u & 31, p2 = u >> 5;
        int4 v = *(const int4*)(tile + p2 * 264 + sub * 8);
        *(int4*)(xbt + ((size_t)b * HW + p0 + p2) * 256 + sub * 8) = v;
    }
    __syncthreads();

    // cross-wave partial-dot reduction through re-used tile memory (12288 B)
    float* red = (float*)tile;
    #pragma unroll
    for (int j = 0; j < 12; ++j)
        red[(g * 64 + px) * 12 + j] = acc[j];
    __syncthreads();

    if (t < 64) {
        float s[12];
        #pragma unroll
        for (int j = 0; j < 12; ++j)
            s[j] = red[(0 * 64 + px) * 12 + j] + red[(1 * 64 + px) * 12 + j] +
                   red[(2 * 64 + px) * 12 + j] + red[(3 * 64 + px) * 12 + j];

        const int p = p0 + px;
        const float pyf = (float)(p / IMG);
        const float pxf = (float)(p % IMG);

        #pragma unroll
        for (int k = 0; k < NK; ++k) {
            float fx = s[k * 2 + 0] + boff[k * 2 + 0];
            float fy = s[k * 2 + 1] + boff[k * 2 + 1];
            float vx = 2.0f * (pxf + fx) / 95.0f - 1.0f;
            float vy = 2.0f * (pyf + fy) / 95.0f - 1.0f;
            float ix = (vx + 1.0f) * 48.0f - 0.5f;
            float iy = (vy + 1.0f) * 48.0f - 0.5f;
            coords[((size_t)k * NB + b) * HW + p] = make_float2(ix, iy);
        }
        float l0 = s[8] + bwt[0], l1 = s[9] + bwt[1];
        float l2 = s[10] + bwt[2], l3 = s[11] + bwt[3];
        float m = fmaxf(fmaxf(l0, l1), fmaxf(l2, l3));
        float e0 = __expf(l0 - m), e1 = __expf(l1 - m);
        float e2 = __expf(l2 - m), e3 = __expf(l3 - m);
        float inv = 1.0f / (e0 + e1 + e2 + e3);
        wts[((size_t)0 * NB + b) * HW + p] = e0 * inv;
        wts[((size_t)1 * NB + b) * HW + p] = e1 * inv;
        wts[((size_t)2 * NB + b) * HW + p] = e2 * inv;
        wts[((size_t)3 * NB + b) * HW + p] = e3 * inv;
    }
}

// ---------------------------------------------------------------------------
// Kernel 2 (FUSED sample+gemm), v2: FULL-M blocks — 256 o x 64 p per block.
// Each pixel is gathered exactly ONCE (was twice with 128x128 tiles) ->
// gather LLC traffic and phase-B VALU both halve.
//   phase A: coords/weights, (px,k) = (t&63, t>>6) parallel -> cw/ci LDS
//   phase B: bilinear gather from xbt -> Bs[64 px][256 c] bf16
//            (chunk swizzle pos = ch ^ (px&7): 512B-row ds_read conflict-free)
//   phase C: K-loop BK=64 (4 steps), As[256][64] via global_load_lds with
//            source-preswizzle sub^(row&7); 32 MFMA/step/wave.
//   Epilogue: out = acc + bc[o]*wsum[p].
// LDS: Bs 32768 + As 32768 + cw 4096 + ci 2048 + wsum 256 = 71936 B
//      -> 2 blocks/CU; co-resident blocks' phases overlap.
// ---------------------------------------------------------------------------
extern "C" __global__ __launch_bounds__(256, 2)
void fused_kernel(const unsigned short* __restrict__ Wcb,
                  const unsigned short* __restrict__ xbt,
                  const float2* __restrict__ coords,
                  const float* __restrict__ wts,
                  const float* __restrict__ bc,
                  float* __restrict__ out)
{
    __shared__ __align__(16) unsigned char lds[71936];
    unsigned short* BsU   = (unsigned short*)lds;             // [64][256] bf16 swz
    unsigned short* AsU   = (unsigned short*)(lds + 32768);   // [256][64] bf16 swz
    float*          cw    = (float*)(lds + 65536);            // [64][16] corner w
    unsigned int*   ci    = (unsigned int*)(lds + 69632);     // [64][8] idx-pairs
    float*          wsumL = (float*)(lds + 71680);            // [64]

    const int t  = threadIdx.x;
    const int bx = blockIdx.x;
    const int b  = bx / 144;
    const int p0 = (bx % 144) * 64;   // p tile (o tile = full 256)

    // ---------------- phase A: per-(pixel,k) coords/weights ----------------
    {
        const int px = t & 63;
        const int k  = t >> 6;
        const int p  = p0 + px;
        float2 cc = coords[((size_t)k * NB + b) * HW + p];
        float wk  = wts[((size_t)k * NB + b) * HW + p];
        float x0f = floorf(cc.x), y0f = floorf(cc.y);
        float wx1 = cc.x - x0f, wx0 = 1.0f - wx1;
        float wy1 = cc.y - y0f, wy0 = 1.0f - wy1;
        int x0 = (int)x0f, y0 = (int)y0f;
        int x1 = x0 + 1,   y1 = y0 + 1;
        float vx0 = (x0 >= 0 && x0 < IMG) ? 1.f : 0.f;
        float vx1 = (x1 >= 0 && x1 < IMG) ? 1.f : 0.f;
        float vy0 = (y0 >= 0 && y0 < IMG) ? 1.f : 0.f;
        float vy1 = (y1 >= 0 && y1 < IMG) ? 1.f : 0.f;
        int cx0 = min(max(x0, 0), IMG - 1), cx1 = min(max(x1, 0), IMG - 1);
        int cy0 = min(max(y0, 0), IMG - 1), cy1 = min(max(y1, 0), IMG - 1);
        int i0 = cy0 * IMG + cx0, i1 = cy0 * IMG + cx1;
        int i2 = cy1 * IMG + cx0, i3 = cy1 * IMG + cx1;
        float w0 = wk * wx0 * wy0 * vx0 * vy0;
        float w1 = wk * wx1 * wy0 * vx1 * vy0;
        float w2 = wk * wx0 * wy1 * vx0 * vy1;
        float w3 = wk * wx1 * wy1 * vx1 * vy1;
        *(float4*)(cw + px * 16 + k * 4) = make_float4(w0, w1, w2, w3);
        uint2 ip;
        ip.x = (unsigned int)i0 | ((unsigned int)i1 << 16);
        ip.y = (unsigned int)i2 | ((unsigned int)i3 << 16);
        *(uint2*)(ci + px * 8 + k * 2) = ip;
    }
    __syncthreads();

    // ---------------- phase B: gather -> Bs (swizzled), wsum ---------------
    {
        if (t < 64) {
            float s = 0.f;
            #pragma unroll
            for (int j = 0; j < 16; ++j) s += cw[t * 16 + j];
            wsumL[t] = s;
        }
        const int pxl = t >> 5, ch = t & 31;
        const unsigned short* gbase = xbt + (size_t)b * HW * 256 + ch * 8;
        #pragma unroll 2
        for (int rep = 0; rep < 8; ++rep) {
            const int px = rep * 8 + pxl;
            float wl[16];
            #pragma unroll
            for (int q = 0; q < 4; ++q) {
                float4 wv = *(const float4*)(cw + px * 16 + q * 4);
                wl[q * 4 + 0] = wv.x; wl[q * 4 + 1] = wv.y;
                wl[q * 4 + 2] = wv.z; wl[q * 4 + 3] = wv.w;
            }
            unsigned int ip[8];
            #pragma unroll
            for (int q = 0; q < 2; ++q) {
                uint4 iv = *(const uint4*)(ci + px * 8 + q * 4);
                ip[q * 4 + 0] = iv.x; ip[q * 4 + 1] = iv.y;
                ip[q * 4 + 2] = iv.z; ip[q * 4 + 3] = iv.w;
            }
            int4 v[16];
            #pragma unroll
            for (int j = 0; j < 16; ++j) {
                unsigned int idx = (ip[j >> 1] >> ((j & 1) * 16)) & 0xFFFFu;
                v[j] = *(const int4*)(gbase + (size_t)idx * 256);
            }
            float acc[8];
            #pragma unroll
            for (int i = 0; i < 8; ++i) acc[i] = 0.f;
            #pragma unroll
            for (int j = 0; j < 16; ++j) {
                const unsigned int* u = (const unsigned int*)&v[j];
                float wj = wl[j];
                #pragma unroll
                for (int q = 0; q < 4; ++q) {
                    float lo = __uint_as_float(u[q] << 16);
                    float hi = __uint_as_float(u[q] & 0xFFFF0000u);
                    acc[2 * q + 0] += wj * lo;
                    acc[2 * q + 1] += wj * hi;
                }
            }
            union { unsigned short h[8]; int4 v4; } pk;
            #pragma unroll
            for (int i = 0; i < 8; ++i) pk.h[i] = f2bf(acc[i]);
            const int pos = ch ^ (px & 7);
            *(int4*)(BsU + px * 256 + pos * 8) = pk.v4;
        }
    }
    __syncthreads();

    // ---------------- phase C: MFMA K-loop (BK=64, 4 steps) ----------------
    const int lane = t & 63, wave = t >> 6;
    const int wm = wave * 64;          // this wave's 64 o-rows
    const int l15 = lane & 15, quad = lane >> 4;

    f32x4 acc[4][4];
    #pragma unroll
    for (int mt = 0; mt < 4; ++mt)
        #pragma unroll
        for (int nt = 0; nt < 4; ++nt)
            acc[mt][nt] = (f32x4){0.f, 0.f, 0.f, 0.f};

    for (int k0 = 0; k0 < 256; k0 += 64) {
        // stage As: 256 rows x 64 k = 32KB, 2048 16B-chunks, 8 insts/thread.
        // LDS dest linear (wave base + lane*16); source chunk preswizzled so
        // read slot s holds global chunk s^(row&7).
        #pragma unroll
        for (int i = 0; i < 8; ++i) {
            int u = t + 256 * i;
            int row = u >> 3, sub = u & 7;
            int sub_g = sub ^ (row & 7);
            __builtin_amdgcn_global_load_lds(
                (const __attribute__((address_space(1))) void*)(Wcb + (size_t)row * 256 + k0 + sub_g * 8),
                (__attribute__((address_space(3))) void*)(AsU + u * 8), 16, 0, 0);
        }
        __syncthreads();
        #pragma unroll
        for (int h = 0; h < 2; ++h) {
            bf16x8 af[4], bf[4];
            #pragma unroll
            for (int mt = 0; mt < 4; ++mt) {
                int row = wm + mt * 16 + l15;
                int pos = (h * 4 + quad) ^ (row & 7);
                af[mt] = *(const bf16x8*)(const void*)(AsU + row * 64 + pos * 8);
            }
            #pragma unroll
            for (int nt = 0; nt < 4; ++nt) {
                int row = nt * 16 + l15;
                int pos = ((k0 >> 3) + h * 4 + quad) ^ (row & 7);
                bf[nt] = *(const bf16x8*)(const void*)(BsU + row * 256 + pos * 8);
            }
            #pragma unroll
            for (int mt = 0; mt < 4; ++mt)
                #pragma unroll
                for (int nt = 0; nt < 4; ++nt)
                    acc[mt][nt] = __builtin_amdgcn_mfma_f32_16x16x32_bf16(af[mt], bf[nt], acc[mt][nt], 0, 0, 0);
        }
        __syncthreads();
    }

    // wsum for this thread's 4 p-columns (from LDS)
    float wv[4];
    #pragma unroll
    for (int nt = 0; nt < 4; ++nt)
        wv[nt] = wsumL[nt * 16 + l15];

    // epilogue: D row = quad*4+reg (o), col = l15 (p); fp32 out + bias*wsum
    #pragma unroll
    for (int mt = 0; mt < 4; ++mt) {
        int ob = wm + mt * 16 + quad * 4;
        #pragma unroll
        for (int reg = 0; reg < 4; ++reg) {
            int o = ob + reg;
            float bias = bc[o];
            float* dst = out + ((size_t)b * 256 + o) * HW + p0 + l15;
            #pragma unroll
            for (int nt = 0; nt < 4; ++nt)
                dst[nt * 16] = acc[mt][nt][reg] + bias * wv[nt];
        }
    }
}

// ---------------------------------------------------------------------------
extern "C" void kernel_launch(void* const* d_in, const int* in_sizes, int n_in,
                              void* d_out, int out_size, void* d_ws, size_t ws_size,
                              hipStream_t stream)
{
    const float* x    = (const float*)d_in[0];
    const float* Wc   = (const float*)d_in[1];
    const float* bc   = (const float*)d_in[2];
    const float* Woff = (const float*)d_in[3];
    const float* boff = (const float*)d_in[4];
    const float* Wwt  = (const float*)d_in[5];
    const float* bwt  = (const float*)d_in[6];
    float* out = (float*)d_out;

    char* ws = (char*)d_ws;
    unsigned short* xbt  = (unsigned short*)(ws);               // 37748736 B
    float2* coords       = (float2*)(ws + 75497472);            // 2359296 B
    float*  wts          = (float*)(ws + 77856768);             // 1179648 B
    unsigned short* Wcb  = (unsigned short*)(ws + 79036416);    // 131072 B

    prep_kernel<<<dim3(NB * 144 + 64), dim3(256), 0, stream>>>(
        x, Wc, Woff, boff, Wwt, bwt, xbt, Wcb, coords, wts);
    fused_kernel<<<dim3(NB * 144), dim3(256), 0, stream>>>(
        Wcb, xbt, coords, wts, bc, out);
}

// Round 5
// 189.568 us; speedup vs baseline: 1.2267x; 1.0370x over previous
//
#include <hip/hip_runtime.h>

#define HW   9216
#define IMG  96
#define NB   8
#define NK   4

typedef __bf16 bf16x8 __attribute__((ext_vector_type(8)));
typedef float  f32x4  __attribute__((ext_vector_type(4)));

__device__ __forceinline__ unsigned short f2bf(float f) {
    unsigned int u = __float_as_uint(f);
    u += 0x7FFFu + ((u >> 16) & 1u);   // round-to-nearest-even (finite inputs)
    return (unsigned short)(u >> 16);
}

// ---------------------------------------------------------------------------
// Kernel 1: prep (+ folded Wc->bf16 conversion in trailing 64 blocks).
// Round-0 structure (best measured 56.7 us). Single change this round:
// tile stride 132 -> 133 dwords (px*5 mod 32, gcd(5,32)=1) so the per-channel
// trow writes are bank-conflict-free (was 8-way). LDS 34048 B, still 4/CU.
// ---------------------------------------------------------------------------
extern "C" __global__ __launch_bounds__(256, 4)
void prep_kernel(const float* __restrict__ x,
                 const float* __restrict__ Wc,
                 const float* __restrict__ Woff,
                 const float* __restrict__ boff,
                 const float* __restrict__ Wwt,
                 const float* __restrict__ bwt,
                 unsigned short* __restrict__ xbt,
                 unsigned short* __restrict__ Wcb,
                 float2* __restrict__ coords,
                 float* __restrict__ wts)
{
    __shared__ __align__(16) unsigned short tile[64 * 266];   // 34048 B

    const int t   = threadIdx.x;
    const int bxr = blockIdx.x;

    if (bxr >= NB * 144) {
        // Wc fp32 -> bf16, row-major [o][c] (A-operand layout). 64 blocks.
        int u = ((bxr - NB * 144) * 256 + t) * 4;
        float4 v = *(const float4*)(Wc + u);
        union { unsigned short h[4]; int2 p; } pk;
        pk.h[0] = f2bf(v.x); pk.h[1] = f2bf(v.y);
        pk.h[2] = f2bf(v.z); pk.h[3] = f2bf(v.w);
        *(int2*)(Wcb + u) = pk.p;
        return;
    }

    const int b  = bxr / 144;
    const int p0 = (bxr % 144) * 64;
    const int px = t & 63;
    const int g  = __builtin_amdgcn_readfirstlane(t >> 6);  // wave-uniform strip

    float acc[12];
    #pragma unroll
    for (int j = 0; j < 12; ++j) acc[j] = 0.f;

    const float* xb = x + ((size_t)(b * 256 + g * 64)) * HW + p0 + px;
    unsigned int* trow = (unsigned int*)tile;

    for (int i0 = 0; i0 < 64; i0 += 8) {
        float v[8];
        #pragma unroll
        for (int q = 0; q < 8; ++q)
            v[q] = xb[(size_t)(i0 + q) * HW];     // 8 independent loads in flight
        #pragma unroll
        for (int q = 0; q < 8; ++q) {
            const int c = g * 64 + i0 + q;        // wave-uniform -> scalar wt loads
            #pragma unroll
            for (int j = 0; j < 8; ++j) acc[j] += v[q] * Woff[j * 256 + c];
            #pragma unroll
            for (int j = 0; j < 4; ++j) acc[8 + j] += v[q] * Wwt[j * 256 + c];
        }
        #pragma unroll
        for (int q = 0; q < 8; q += 2) {
            unsigned int pk = (unsigned int)f2bf(v[q]) | ((unsigned int)f2bf(v[q + 1]) << 16);
            trow[px * 133 + ((g * 64 + i0 + q) >> 1)] = pk;
        }
    }

    __syncthreads();
    // pack xbt: 64 px x 256 c bf16, int4 stores (lanes 0-31 = contiguous 512 B)
    #pragma unroll
    for (int r = 0; r < 8; ++r) {
        int u = t + 256 * r;
        int sub = u & 31, p2 = u >> 5;
        int4 v = *(const int4*)(tile + p2 * 266 + sub * 8);
        *(int4*)(xbt + ((size_t)b * HW + p0 + p2) * 256 + sub * 8) = v;
    }
    __syncthreads();

    // cross-wave partial-dot reduction through re-used tile memory (12288 B)
    float* red = (float*)tile;
    #pragma unroll
    for (int j = 0; j < 12; ++j)
        red[(g * 64 + px) * 12 + j] = acc[j];
    __syncthreads();

    if (t < 64) {
        float s[12];
        #pragma unroll
        for (int j = 0; j < 12; ++j)
            s[j] = red[(0 * 64 + px) * 12 + j] + red[(1 * 64 + px) * 12 + j] +
                   red[(2 * 64 + px) * 12 + j] + red[(3 * 64 + px) * 12 + j];

        const int p = p0 + px;
        const float pyf = (float)(p / IMG);
        const float pxf = (float)(p % IMG);

        #pragma unroll
        for (int k = 0; k < NK; ++k) {
            float fx = s[k * 2 + 0] + boff[k * 2 + 0];
            float fy = s[k * 2 + 1] + boff[k * 2 + 1];
            float vx = 2.0f * (pxf + fx) / 95.0f - 1.0f;
            float vy = 2.0f * (pyf + fy) / 95.0f - 1.0f;
            float ix = (vx + 1.0f) * 48.0f - 0.5f;
            float iy = (vy + 1.0f) * 48.0f - 0.5f;
            coords[((size_t)k * NB + b) * HW + p] = make_float2(ix, iy);
        }
        float l0 = s[8] + bwt[0], l1 = s[9] + bwt[1];
        float l2 = s[10] + bwt[2], l3 = s[11] + bwt[3];
        float m = fmaxf(fmaxf(l0, l1), fmaxf(l2, l3));
        float e0 = __expf(l0 - m), e1 = __expf(l1 - m);
        float e2 = __expf(l2 - m), e3 = __expf(l3 - m);
        float inv = 1.0f / (e0 + e1 + e2 + e3);
        wts[((size_t)0 * NB + b) * HW + p] = e0 * inv;
        wts[((size_t)1 * NB + b) * HW + p] = e1 * inv;
        wts[((size_t)2 * NB + b) * HW + p] = e2 * inv;
        wts[((size_t)3 * NB + b) * HW + p] = e3 * inv;
    }
}

// ---------------------------------------------------------------------------
// Kernel 2 (FUSED sample+gemm), v3: 256 o x 64 p per block, 3 blocks/CU.
//   - XCD-chunked swizzle: b = bx&7, tile = bx>>3  (1152 = 8 XCD x 144) ->
//     each XCD's L2 holds only its batch's 4.7 MB xbt slice (was 37.7 MB).
//   - BK=32 K-loop (8 steps), As[256][32]=16KB single-buffer, cw/ci aliased
//     under As (dead after phase B barrier) -> LDS 49408 B -> 3 blocks/CU.
//   phase A: coords/weights (px,k)=(t&63,t>>6) -> cw/ci
//   phase B: bilinear gather -> Bs[64][256] bf16, chunk swz pos=ch^(px&7)
//   phase C: As via global_load_lds, source-preswizzle sub^((row>>1)&3);
//            16 MFMA/step/wave. Epilogue: out = acc + bc[o]*wsum[p].
// ---------------------------------------------------------------------------
extern "C" __global__ __launch_bounds__(256, 3)
void fused_kernel(const unsigned short* __restrict__ Wcb,
                  const unsigned short* __restrict__ xbt,
                  const float2* __restrict__ coords,
                  const float* __restrict__ wts,
                  const float* __restrict__ bc,
                  float* __restrict__ out)
{
    __shared__ __align__(16) unsigned char lds[49408];
    unsigned short* BsU   = (unsigned short*)lds;             // [64][256] bf16 swz
    unsigned short* AsU   = (unsigned short*)(lds + 32768);   // [256][32] bf16 swz (phase C)
    float*          cw    = (float*)(lds + 32768);            // [64][16] w   (A/B, aliases As)
    unsigned int*   ci    = (unsigned int*)(lds + 36864);     // [64][8] idx  (A/B, aliases As)
    float*          wsumL = (float*)(lds + 49152);            // [64] (NOT aliased)

    const int t  = threadIdx.x;
    const int bx = blockIdx.x;
    const int b  = bx & 7;            // XCD-chunked: one batch per XCD
    const int p0 = (bx >> 3) * 64;    // p tile (o tile = full 256)

    // ---------------- phase A: per-(pixel,k) coords/weights ----------------
    {
        const int px = t & 63;
        const int k  = t >> 6;
        const int p  = p0 + px;
        float2 cc = coords[((size_t)k * NB + b) * HW + p];
        float wk  = wts[((size_t)k * NB + b) * HW + p];
        float x0f = floorf(cc.x), y0f = floorf(cc.y);
        float wx1 = cc.x - x0f, wx0 = 1.0f - wx1;
        float wy1 = cc.y - y0f, wy0 = 1.0f - wy1;
        int x0 = (int)x0f, y0 = (int)y0f;
        int x1 = x0 + 1,   y1 = y0 + 1;
        float vx0 = (x0 >= 0 && x0 < IMG) ? 1.f : 0.f;
        float vx1 = (x1 >= 0 && x1 < IMG) ? 1.f : 0.f;
        float vy0 = (y0 >= 0 && y0 < IMG) ? 1.f : 0.f;
        float vy1 = (y1 >= 0 && y1 < IMG) ? 1.f : 0.f;
        int cx0 = min(max(x0, 0), IMG - 1), cx1 = min(max(x1, 0), IMG - 1);
        int cy0 = min(max(y0, 0), IMG - 1), cy1 = min(max(y1, 0), IMG - 1);
        int i0 = cy0 * IMG + cx0, i1 = cy0 * IMG + cx1;
        int i2 = cy1 * IMG + cx0, i3 = cy1 * IMG + cx1;
        float w0 = wk * wx0 * wy0 * vx0 * vy0;
        float w1 = wk * wx1 * wy0 * vx1 * vy0;
        float w2 = wk * wx0 * wy1 * vx0 * vy1;
        float w3 = wk * wx1 * wy1 * vx1 * vy1;
        *(float4*)(cw + px * 16 + k * 4) = make_float4(w0, w1, w2, w3);
        uint2 ip;
        ip.x = (unsigned int)i0 | ((unsigned int)i1 << 16);
        ip.y = (unsigned int)i2 | ((unsigned int)i3 << 16);
        *(uint2*)(ci + px * 8 + k * 2) = ip;
    }
    __syncthreads();

    // ---------------- phase B: gather -> Bs (swizzled), wsum ---------------
    {
        if (t < 64) {
            float s = 0.f;
            #pragma unroll
            for (int j = 0; j < 16; ++j) s += cw[t * 16 + j];
            wsumL[t] = s;
        }
        const int pxl = t >> 5, ch = t & 31;
        const unsigned short* gbase = xbt + (size_t)b * HW * 256 + ch * 8;
        #pragma unroll 2
        for (int rep = 0; rep < 8; ++rep) {
            const int px = rep * 8 + pxl;
            float wl[16];
            #pragma unroll
            for (int q = 0; q < 4; ++q) {
                float4 wv = *(const float4*)(cw + px * 16 + q * 4);
                wl[q * 4 + 0] = wv.x; wl[q * 4 + 1] = wv.y;
                wl[q * 4 + 2] = wv.z; wl[q * 4 + 3] = wv.w;
            }
            unsigned int ip[8];
            #pragma unroll
            for (int q = 0; q < 2; ++q) {
                uint4 iv = *(const uint4*)(ci + px * 8 + q * 4);
                ip[q * 4 + 0] = iv.x; ip[q * 4 + 1] = iv.y;
                ip[q * 4 + 2] = iv.z; ip[q * 4 + 3] = iv.w;
            }
            int4 v[16];
            #pragma unroll
            for (int j = 0; j < 16; ++j) {
                unsigned int idx = (ip[j >> 1] >> ((j & 1) * 16)) & 0xFFFFu;
                v[j] = *(const int4*)(gbase + (size_t)idx * 256);
            }
            float acc[8];
            #pragma unroll
            for (int i = 0; i < 8; ++i) acc[i] = 0.f;
            #pragma unroll
            for (int j = 0; j < 16; ++j) {
                const unsigned int* u = (const unsigned int*)&v[j];
                float wj = wl[j];
                #pragma unroll
                for (int q = 0; q < 4; ++q) {
                    float lo = __uint_as_float(u[q] << 16);
                    float hi = __uint_as_float(u[q] & 0xFFFF0000u);
                    acc[2 * q + 0] += wj * lo;
                    acc[2 * q + 1] += wj * hi;
                }
            }
            union { unsigned short h[8]; int4 v4; } pk;
            #pragma unroll
            for (int i = 0; i < 8; ++i) pk.h[i] = f2bf(acc[i]);
            const int pos = ch ^ (px & 7);
            *(int4*)(BsU + px * 256 + pos * 8) = pk.v4;
        }
    }
    __syncthreads();   // after this, cw/ci are dead -> As may overwrite them

    // ---------------- phase C: MFMA K-loop (BK=32, 8 steps) ----------------
    const int lane = t & 63, wave = t >> 6;
    const int wm = wave * 64;          // this wave's 64 o-rows
    const int l15 = lane & 15, quad = lane >> 4;

    f32x4 acc[4][4];
    #pragma unroll
    for (int mt = 0; mt < 4; ++mt)
        #pragma unroll
        for (int nt = 0; nt < 4; ++nt)
            acc[mt][nt] = (f32x4){0.f, 0.f, 0.f, 0.f};

    for (int k0 = 0; k0 < 256; k0 += 32) {
        // stage As: 256 rows x 32 k = 16KB, 1024 16B-chunks, 4 insts/thread.
        // LDS dest linear (wave base + lane*16); source chunk preswizzled so
        // read slot s holds global chunk s^((row>>1)&3).
        #pragma unroll
        for (int i = 0; i < 4; ++i) {
            int u = t + 256 * i;
            int row = u >> 2, sub = u & 3;
            int sub_g = sub ^ ((row >> 1) & 3);
            __builtin_amdgcn_global_load_lds(
                (const __attribute__((address_space(1))) void*)(Wcb + (size_t)row * 256 + k0 + sub_g * 8),
                (__attribute__((address_space(3))) void*)(AsU + u * 8), 16, 0, 0);
        }
        __syncthreads();
        bf16x8 af[4], bf[4];
        #pragma unroll
        for (int mt = 0; mt < 4; ++mt) {
            int row = wm + mt * 16 + l15;
            int pos = quad ^ ((row >> 1) & 3);
            af[mt] = *(const bf16x8*)(const void*)(AsU + row * 32 + pos * 8);
        }
        #pragma unroll
        for (int nt = 0; nt < 4; ++nt) {
            int row = nt * 16 + l15;
            int pos = ((k0 >> 3) + quad) ^ (row & 7);
            bf[nt] = *(const bf16x8*)(const void*)(BsU + row * 256 + pos * 8);
        }
        #pragma unroll
        for (int mt = 0; mt < 4; ++mt)
            #pragma unroll
            for (int nt = 0; nt < 4; ++nt)
                acc[mt][nt] = __builtin_amdgcn_mfma_f32_16x16x32_bf16(af[mt], bf[nt], acc[mt][nt], 0, 0, 0);
        __syncthreads();
    }

    // wsum for this thread's 4 p-columns (from LDS)
    float wv[4];
    #pragma unroll
    for (int nt = 0; nt < 4; ++nt)
        wv[nt] = wsumL[nt * 16 + l15];

    // epilogue: D row = quad*4+reg (o), col = l15 (p); fp32 out + bias*wsum
    #pragma unroll
    for (int mt = 0; mt < 4; ++mt) {
        int ob = wm + mt * 16 + quad * 4;
        #pragma unroll
        for (int reg = 0; reg < 4; ++reg) {
            int o = ob + reg;
            float bias = bc[o];
            float* dst = out + ((size_t)b * 256 + o) * HW + p0 + l15;
            #pragma unroll
            for (int nt = 0; nt < 4; ++nt)
                dst[nt * 16] = acc[mt][nt][reg] + bias * wv[nt];
        }
    }
}

// ---------------------------------------------------------------------------
extern "C" void kernel_launch(void* const* d_in, const int* in_sizes, int n_in,
                              void* d_out, int out_size, void* d_ws, size_t ws_size,
                              hipStream_t stream)
{
    const float* x    = (const float*)d_in[0];
    const float* Wc   = (const float*)d_in[1];
    const float* bc   = (const float*)d_in[2];
    const float* Woff = (const float*)d_in[3];
    const float* boff = (const float*)d_in[4];
    const float* Wwt  = (const float*)d_in[5];
    const float* bwt  = (const float*)d_in[6];
    float* out = (float*)d_out;

    char* ws = (char*)d_ws;
    unsigned short* xbt  = (unsigned short*)(ws);               // 37748736 B
    float2* coords       = (float2*)(ws + 75497472);            // 2359296 B
    float*  wts          = (float*)(ws + 77856768);             // 1179648 B
    unsigned short* Wcb  = (unsigned short*)(ws + 79036416);    // 131072 B

    prep_kernel<<<dim3(NB * 144 + 64), dim3(256), 0, stream>>>(
        x, Wc, Woff, boff, Wwt, bwt, xbt, Wcb, coords, wts);
    fused_kernel<<<dim3(NB * 144), dim3(256), 0, stream>>>(
        Wcb, xbt, coords, wts, bc, out);
}